// Round 9
// baseline (295.940 us; speedup 1.0000x reference)
//
#include <hip/hip_runtime.h>
#include <hip/hip_bf16.h>
#include <math.h>

#define N_NODES 40000
#define N_EDGES 640000
#define D 128
#define N_GRAPHS 128
#define SCAN_NBLK ((N_NODES + 255) / 256)   // 157
#define LDS_STRIDE 68                        // words per agg row (pad vs 64 to spread banks)

typedef __attribute__((ext_vector_type(8))) short bf16x8;
typedef __attribute__((ext_vector_type(4))) float f32x4;
typedef __attribute__((ext_vector_type(4))) unsigned int u32x4;

static __device__ __forceinline__ unsigned short f2b(float f) {
    unsigned int u = __float_as_uint(f);
    unsigned int r = (u + 0x7fffu + ((u >> 16) & 1u)) >> 16;  // RNE
    return (unsigned short)r;
}
static __device__ __forceinline__ float blo(unsigned int u) {
    return __uint_as_float(u << 16);
}
static __device__ __forceinline__ float bhi(unsigned int u) {
    return __uint_as_float(u & 0xffff0000u);
}
// monotonic f32 -> u32 key (unsigned order == float order)
static __device__ __forceinline__ unsigned int fkey(float x) {
    unsigned int b = __float_as_uint(x);
    return (b & 0x80000000u) ? ~b : (b | 0x80000000u);
}

// ---- init: zero counts + bucket hist + dummy rows, seed out keys -----------
__global__ void __launch_bounds__(256) k_init(
    int* __restrict__ counts, int* __restrict__ kbuf,
    unsigned short* __restrict__ xb, unsigned short* __restrict__ hA,
    unsigned short* __restrict__ hB, unsigned int* __restrict__ outk) {
    int n = blockIdx.x * 256 + threadIdx.x;
    if (n < N_GRAPHS * D) outk[n] = 0x007FFFFFu;   // key(-inf)
    if (n < 1024) kbuf[n] = 0;
    if (n < N_NODES) counts[n] = 0;
    if (blockIdx.x == SCAN_NBLK) {   // block 157: zero the 3 dummy rows
        int t = threadIdx.x;
        if (t < 48) {
            int row = t >> 4, c = t & 15;
            unsigned short* p = (row == 0) ? xb : (row == 1) ? hA : hB;
            u32x4 z = {0u, 0u, 0u, 0u};
            ((u32x4*)(p + (size_t)N_NODES * D))[c] = z;
        }
    }
}

// ---- packed: hist (2500 blk) + x2b (2500 blk) + wprep3 (384 blk) -----------
__global__ void __launch_bounds__(256) k_pack1(
    const int* __restrict__ ei, int* __restrict__ counts,
    const float* __restrict__ x, unsigned int* __restrict__ xb,
    const float* __restrict__ Wr0, const float* __restrict__ Wt0,
    const float* __restrict__ Wr1, const float* __restrict__ Wt1,
    const float* __restrict__ Wr2, const float* __restrict__ Wt2,
    unsigned short* __restrict__ WT) {
    int b = blockIdx.x;
    int t = threadIdx.x;
    if (b < 2500) {
        int e = b * 256 + t;
        atomicAdd(&counts[ei[N_EDGES + e]], 1);
    } else if (b < 5000) {
        int i = (b - 2500) * 256 + t;
        const f32x4* xv = (const f32x4*)x;
        f32x4 v0 = xv[i * 2], v1 = xv[i * 2 + 1];
        u32x4 o;
        o.x = ((unsigned int)f2b(v0.y) << 16) | f2b(v0.x);
        o.y = ((unsigned int)f2b(v0.w) << 16) | f2b(v0.z);
        o.z = ((unsigned int)f2b(v1.y) << 16) | f2b(v1.x);
        o.w = ((unsigned int)f2b(v1.w) << 16) | f2b(v1.z);
        ((u32x4*)xb)[i] = o;
    } else {
        int bw = b - 5000;                 // 0..383
        int l = bw >> 7, c = bw & 127, k = t;
        const float* Wrel = (l == 0) ? Wr0 : (l == 1) ? Wr1 : Wr2;
        const float* Wroot = (l == 0) ? Wt0 : (l == 1) ? Wt1 : Wt2;
        float v = (k < D) ? Wrel[k * D + c] : Wroot[(k - D) * D + c];
        WT[(size_t)l * 128 * 256 + c * 256 + k] = f2b(v);
    }
}

// ---- scan of padded (x16) degrees ------------------------------------------
__global__ void __launch_bounds__(256) k_scan1(const int* __restrict__ counts,
                                               int* __restrict__ local_pre,
                                               int* __restrict__ blocksums) {
    int t = threadIdx.x;
    int i = blockIdx.x * 256 + t;
    int lane = t & 63, wave = t >> 6;
    int v = (i < N_NODES) ? ((counts[i] + 15) & ~15) : 0;   // pad degree to x16
    int incl = v;
#pragma unroll
    for (int off = 1; off < 64; off <<= 1) {
        int u = __shfl_up(incl, off);
        if (lane >= off) incl += u;
    }
    __shared__ int ws[4];
    if (lane == 63) ws[wave] = incl;
    __syncthreads();
    int base = 0;
    for (int w = 0; w < 4; ++w) {
        int s = ws[w];
        if (w < wave) base += s;
    }
    if (i < N_NODES) local_pre[i] = base + incl - v;
    if (t == 255) blocksums[blockIdx.x] = base + incl;
}

// Fused scan2+scan3: block reduces blocksums[0..bid), emits row starts +
// cursor + dummy fill + (batch,ntrips) bucket histogram for the node sort.
__global__ void __launch_bounds__(256) k_scan3(const int* __restrict__ local_pre,
                                               const int* __restrict__ blocksums,
                                               const int* __restrict__ counts,
                                               const int* __restrict__ batch,
                                               int* __restrict__ rp_pad,
                                               int* __restrict__ cursor,
                                               int* __restrict__ src_pad,
                                               int* __restrict__ kbuf) {
    int t = threadIdx.x;
    int lane = t & 63, wave = t >> 6;
    int bid = blockIdx.x;
    int v = (t < bid) ? blocksums[t] : 0;   // bid <= 156 < 256
#pragma unroll
    for (int off = 32; off >= 1; off >>= 1) v += __shfl_xor(v, off);
    __shared__ int ws[4];
    if (lane == 0) ws[wave] = v;
    __syncthreads();
    int base = ws[0] + ws[1] + ws[2] + ws[3];   // exclusive prefix for this block

    int i = bid * 256 + t;
    if (i < N_NODES) {
        int rp = base + local_pre[i];
        rp_pad[i] = rp;
        cursor[i] = rp;
        int c = counts[i];
        int pc = (c + 15) & ~15;
        for (int j = rp + c; j < rp + pc; ++j) src_pad[j] = N_NODES;
        if (i == N_NODES - 1) rp_pad[N_NODES] = rp + pc;
        int nt = pc >> 4;
        if (nt > 7) nt = 7;
        atomicAdd(&kbuf[batch[i] * 8 + nt], 1);
    }
}

// exclusive prefix over the 1024 bucket counts (in place)
__global__ void __launch_bounds__(1024) k_kprefix(int* __restrict__ kbuf) {
    int t = threadIdx.x;
    int lane = t & 63, wave = t >> 6;   // 16 waves
    int v = kbuf[t];
    int incl = v;
#pragma unroll
    for (int off = 1; off < 64; off <<= 1) {
        int u = __shfl_up(incl, off);
        if (lane >= off) incl += u;
    }
    __shared__ int ws[16];
    if (lane == 63) ws[wave] = incl;
    __syncthreads();
    int base = 0;
    for (int w = 0; w < 16; ++w) {
        int s = ws[w];
        if (w < wave) base += s;
    }
    kbuf[t] = base + incl - v;
}

// scatter node ids into perm, bucketed by (graph, ntrips)
__global__ void __launch_bounds__(256) k_sortnodes(const int* __restrict__ rp_pad,
                                                   const int* __restrict__ batch,
                                                   int* __restrict__ kbuf,
                                                   int* __restrict__ perm) {
    int i = blockIdx.x * 256 + threadIdx.x;
    if (i >= N_NODES) return;
    int nt = (rp_pad[i + 1] - rp_pad[i]) >> 4;
    if (nt > 7) nt = 7;
    int pos = atomicAdd(&kbuf[batch[i] * 8 + nt], 1);
    perm[pos] = i;
}

__global__ void k_scatter(const int* __restrict__ ei, int* __restrict__ cursor,
                          int* __restrict__ src_pad) {
    int e = blockIdx.x * blockDim.x + threadIdx.x;
    if (e < N_EDGES) {
        int d = ei[N_EDGES + e];
        int pos = atomicAdd(&cursor[d], 1);
        src_pad[pos] = ei[e];
    }
}

// ---- fused layer: CSR gather-sum (LDS) + MFMA GEMM (+ fused max-pool) ------
// Block = 16 nodes taken from perm[] (bucketed by (graph,ntrips) -> blocks are
// trip-count homogeneous; kills the __syncthreads convoy). 4 waves; lane =
// (q = node slot lane>>4, c = chunk lane&15). Phase 1: 16 group-uniform
// full-row reads per trip. Phase 2: GEMM out[16][128] = [aggLDS|X]@WT + b.
// Epilogue: outk==null -> relu+store bf16; else fused global_max_pool.
__global__ void __launch_bounds__(256) k_layer(
    const unsigned short* __restrict__ in,  // [N+1][128] bf16 (row N zero)
    const int* __restrict__ rp_pad,
    const int* __restrict__ src_pad,
    const int* __restrict__ perm,
    const unsigned short* __restrict__ WT,  // [128][256] bf16 (k contiguous)
    const float* __restrict__ bias,
    unsigned short* __restrict__ out,       // [N+1][128] bf16 (unused if outk)
    const int* __restrict__ batch,
    unsigned int* __restrict__ outk) {      // null for layers 0,1
    __shared__ unsigned int aggLDS[16 * LDS_STRIDE];
    __shared__ int permLDS[16];
    int tid = threadIdx.x;
    int w = tid >> 6;
    int lane = tid & 63;
    int q = lane >> 4;      // node slot / MFMA quad
    int c = lane & 15;      // 16B chunk / MFMA row
    int nl = w * 4 + q;
    int nodebase = blockIdx.x * 16;
    const u32x4* inv = (const u32x4*)in;

    // ---- phase 1: gather-sum ----
    int pn = perm[nodebase + nl];           // group-uniform
    if (c == 0) permLDS[nl] = pn;
    int s = rp_pad[pn];
    int e = rp_pad[pn + 1];
    const int4* sidx = (const int4*)(src_pad + s);
    int ntrips = (e - s) >> 4;

    float a0 = 0.f, a1 = 0.f, a2 = 0.f, a3 = 0.f;
    float a4 = 0.f, a5 = 0.f, a6 = 0.f, a7 = 0.f;

#define ACC8(v) do { \
        a0 += blo((v).x); a1 += bhi((v).x); \
        a2 += blo((v).y); a3 += bhi((v).y); \
        a4 += blo((v).z); a5 += bhi((v).z); \
        a6 += blo((v).w); a7 += bhi((v).w); } while (0)

    for (int t = 0; t < ntrips; ++t) {
        int4 ia = sidx[4 * t + 0];
        int4 ib = sidx[4 * t + 1];
        int4 ic = sidx[4 * t + 2];
        int4 id = sidx[4 * t + 3];
        u32x4 v0 = inv[ia.x * 16 + c];
        u32x4 v1 = inv[ia.y * 16 + c];
        u32x4 v2 = inv[ia.z * 16 + c];
        u32x4 v3 = inv[ia.w * 16 + c];
        u32x4 v4 = inv[ib.x * 16 + c];
        u32x4 v5 = inv[ib.y * 16 + c];
        u32x4 v6 = inv[ib.z * 16 + c];
        u32x4 v7 = inv[ib.w * 16 + c];
        u32x4 v8 = inv[ic.x * 16 + c];
        u32x4 v9 = inv[ic.y * 16 + c];
        u32x4 va = inv[ic.z * 16 + c];
        u32x4 vb = inv[ic.w * 16 + c];
        u32x4 vc = inv[id.x * 16 + c];
        u32x4 vd = inv[id.y * 16 + c];
        u32x4 ve = inv[id.z * 16 + c];
        u32x4 vf = inv[id.w * 16 + c];
        ACC8(v0); ACC8(v1); ACC8(v2); ACC8(v3);
        ACC8(v4); ACC8(v5); ACC8(v6); ACC8(v7);
        ACC8(v8); ACC8(v9); ACC8(va); ACC8(vb);
        ACC8(vc); ACC8(vd); ACC8(ve); ACC8(vf);
    }
#undef ACC8

    u32x4 o;
    o.x = ((unsigned int)f2b(a1) << 16) | f2b(a0);
    o.y = ((unsigned int)f2b(a3) << 16) | f2b(a2);
    o.z = ((unsigned int)f2b(a5) << 16) | f2b(a4);
    o.w = ((unsigned int)f2b(a7) << 16) | f2b(a6);
    *(u32x4*)&aggLDS[nl * LDS_STRIDE + c * 4] = o;   // linear feats: word i = feats 2i,2i+1
    __syncthreads();

    // ---- phase 2: GEMM ----
    int row = c, quad = q;
    int colbase = w * 32;
    int prow = permLDS[row];

    f32x4 acc0 = {0.f, 0.f, 0.f, 0.f};
    f32x4 acc1 = {0.f, 0.f, 0.f, 0.f};

    const unsigned int* Al = &aggLDS[row * LDS_STRIDE];
    const short* Xp = (const short*)(in + (size_t)prow * D);
    const short* W0 = (const short*)(WT + (colbase + row) * 256);
    const short* W1 = (const short*)(WT + (colbase + 16 + row) * 256);

#pragma unroll
    for (int t = 0; t < 4; ++t) {
        bf16x8 af = *(const bf16x8*)(Al + t * 16 + quad * 4);
        int k0 = t * 32 + quad * 8;
        bf16x8 b0 = *(const bf16x8*)(W0 + k0);
        bf16x8 b1 = *(const bf16x8*)(W1 + k0);
        acc0 = __builtin_amdgcn_mfma_f32_16x16x32_bf16(af, b0, acc0, 0, 0, 0);
        acc1 = __builtin_amdgcn_mfma_f32_16x16x32_bf16(af, b1, acc1, 0, 0, 0);
    }
#pragma unroll
    for (int t = 0; t < 4; ++t) {
        int k0 = t * 32 + quad * 8;
        bf16x8 xf = *(const bf16x8*)(Xp + k0);
        bf16x8 b0 = *(const bf16x8*)(W0 + 128 + k0);
        bf16x8 b1 = *(const bf16x8*)(W1 + 128 + k0);
        acc0 = __builtin_amdgcn_mfma_f32_16x16x32_bf16(xf, b0, acc0, 0, 0, 0);
        acc1 = __builtin_amdgcn_mfma_f32_16x16x32_bf16(xf, b1, acc1, 0, 0, 0);
    }

    int c0 = colbase + row, c1 = c0 + 16;
    float bia0 = bias[c0], bia1 = bias[c1];
    float v0[4], v1[4];
#pragma unroll
    for (int r = 0; r < 4; ++r) { v0[r] = acc0[r] + bia0; v1[r] = acc1[r] + bia1; }

    if (outk == nullptr) {
        // layers 0,1: relu + bf16 store (permuted rows; 32B runs per quad)
#pragma unroll
        for (int r = 0; r < 4; ++r) {
            int pn2 = permLDS[quad * 4 + r];
            out[(size_t)pn2 * D + c0] = f2b(fmaxf(v0[r], 0.f));
            out[(size_t)pn2 * D + c1] = f2b(fmaxf(v1[r], 0.f));
        }
    } else {
        // layer 2: fused global_max_pool (perm is graph-major -> blocks span
        // one graph except at graph boundaries)
        int g0 = batch[permLDS[0]];
        int g15 = batch[permLDS[15]];
        if (g0 == g15) {
            float m0 = fmaxf(fmaxf(v0[0], v0[1]), fmaxf(v0[2], v0[3]));
            float m1 = fmaxf(fmaxf(v1[0], v1[1]), fmaxf(v1[2], v1[3]));
            m0 = fmaxf(m0, __shfl_xor(m0, 16)); m0 = fmaxf(m0, __shfl_xor(m0, 32));
            m1 = fmaxf(m1, __shfl_xor(m1, 16)); m1 = fmaxf(m1, __shfl_xor(m1, 32));
            if (quad == 0) {
                atomicMax(&outk[g0 * D + c0], fkey(m0));
                atomicMax(&outk[g0 * D + c1], fkey(m1));
            }
        } else {  // boundary block (~5%): per-value atomics
#pragma unroll
            for (int r = 0; r < 4; ++r) {
                int gg = batch[permLDS[quad * 4 + r]];
                atomicMax(&outk[gg * D + c0], fkey(v0[r]));
                atomicMax(&outk[gg * D + c1], fkey(v1[r]));
            }
        }
    }
}

// ---- unmap keys -> floats (in place over d_out) ----------------------------
__global__ void k_unmap(unsigned int* __restrict__ outk) {
    int i = blockIdx.x * 256 + threadIdx.x;   // 64 blocks x 256 = 16384
    unsigned int k = outk[i];
    unsigned int b = (k & 0x80000000u) ? (k ^ 0x80000000u) : ~k;
    ((float*)outk)[i] = __uint_as_float(b);
}

extern "C" void kernel_launch(void* const* d_in, const int* in_sizes, int n_in,
                              void* d_out, int out_size, void* d_ws, size_t ws_size,
                              hipStream_t stream) {
    const float* x = (const float*)d_in[0];
    const int* ei = (const int*)d_in[1];
    const int* batch = (const int*)d_in[2];
    const float* Wrel[3]  = {(const float*)d_in[3], (const float*)d_in[6], (const float*)d_in[9]};
    const float* brel[3]  = {(const float*)d_in[4], (const float*)d_in[7], (const float*)d_in[10]};
    const float* Wroot[3] = {(const float*)d_in[5], (const float*)d_in[8], (const float*)d_in[11]};
    unsigned int* outk = (unsigned int*)d_out;

    char* ws = (char*)d_ws;
    size_t off = 0;
    auto alloc = [&](size_t bytes) -> void* {
        void* p = ws + off;
        off = (off + bytes + 255) & ~(size_t)255;
        return p;
    };
    // activation buffers have one extra zero row (index N_NODES)
    unsigned short* xb  = (unsigned short*)alloc((size_t)(N_NODES + 1) * D * 2);
    unsigned short* hA  = (unsigned short*)alloc((size_t)(N_NODES + 1) * D * 2);
    unsigned short* hB  = (unsigned short*)alloc((size_t)(N_NODES + 1) * D * 2);
    unsigned short* WT  = (unsigned short*)alloc((size_t)3 * 128 * 256 * 2);
    int* rp_pad     = (int*)alloc((size_t)(N_NODES + 1) * 4);
    int* counts     = (int*)alloc((size_t)N_NODES * 4);
    int* cursor     = (int*)alloc((size_t)N_NODES * 4);
    int* src_pad    = (int*)alloc((size_t)(N_EDGES + 16 * N_NODES) * 4);
    int* local_pre  = (int*)alloc((size_t)N_NODES * 4);
    int* blocksums  = (int*)alloc((size_t)SCAN_NBLK * 4);
    int* kbuf       = (int*)alloc((size_t)1024 * 4);
    int* perm       = (int*)alloc((size_t)N_NODES * 4);

    // init (zero counts + buckets + dummy rows + out keys)
    k_init<<<SCAN_NBLK + 1, 256, 0, stream>>>(counts, kbuf, xb, hA, hB, outk);
    // packed: hist + x2b + wprep3
    k_pack1<<<5384, 256, 0, stream>>>(ei, counts, x, (unsigned int*)xb,
                                      Wrel[0], Wroot[0], Wrel[1], Wroot[1],
                                      Wrel[2], Wroot[2], WT);
    // scan (padded degrees) + dummy fill + bucket hist
    k_scan1<<<SCAN_NBLK, 256, 0, stream>>>(counts, local_pre, blocksums);
    k_scan3<<<SCAN_NBLK, 256, 0, stream>>>(local_pre, blocksums, counts, batch,
                                           rp_pad, cursor, src_pad, kbuf);
    // node permutation: counting sort by (graph, ntrips)
    k_kprefix<<<1, 1024, 0, stream>>>(kbuf);
    k_sortnodes<<<SCAN_NBLK, 256, 0, stream>>>(rp_pad, batch, kbuf, perm);
    // CSR scatter
    k_scatter<<<(N_EDGES + 255) / 256, 256, 0, stream>>>(ei, cursor, src_pad);

    // 3 fused GraphConv layers; layer 2 folds the global max pool
    k_layer<<<N_NODES / 16, 256, 0, stream>>>(xb, rp_pad, src_pad, perm, WT,
                                              brel[0], hA, batch, nullptr);
    k_layer<<<N_NODES / 16, 256, 0, stream>>>(hA, rp_pad, src_pad, perm, WT + 128 * 256,
                                              brel[1], hB, batch, nullptr);
    k_layer<<<N_NODES / 16, 256, 0, stream>>>(hB, rp_pad, src_pad, perm, WT + 2 * 128 * 256,
                                              brel[2], hB, batch, outk);

    // keys -> floats
    k_unmap<<<N_GRAPHS * D / 256, 256, 0, stream>>>(outk);
}

// Round 10
// 281.867 us; speedup vs baseline: 1.0499x; 1.0499x over previous
//
#include <hip/hip_runtime.h>
#include <hip/hip_bf16.h>
#include <math.h>

#define N_NODES 40000
#define N_EDGES 640000
#define D 128
#define N_GRAPHS 128
#define SCAN_NBLK ((N_NODES + 255) / 256)   // 157
#define LDS_STRIDE 68                        // words per agg row (pad vs 64 to spread banks)

typedef __attribute__((ext_vector_type(8))) short bf16x8;
typedef __attribute__((ext_vector_type(4))) float f32x4;
typedef __attribute__((ext_vector_type(4))) unsigned int u32x4;

static __device__ __forceinline__ unsigned short f2b(float f) {
    unsigned int u = __float_as_uint(f);
    unsigned int r = (u + 0x7fffu + ((u >> 16) & 1u)) >> 16;  // RNE
    return (unsigned short)r;
}
static __device__ __forceinline__ float blo(unsigned int u) {
    return __uint_as_float(u << 16);
}
static __device__ __forceinline__ float bhi(unsigned int u) {
    return __uint_as_float(u & 0xffff0000u);
}
// monotonic f32 -> u32 key (unsigned order == float order)
static __device__ __forceinline__ unsigned int fkey(float x) {
    unsigned int b = __float_as_uint(x);
    return (b & 0x80000000u) ? ~b : (b | 0x80000000u);
}

// ---- init: zero counts + dummy rows, seed out keys -------------------------
__global__ void __launch_bounds__(256) k_init(
    int* __restrict__ counts,
    unsigned short* __restrict__ xb, unsigned short* __restrict__ hA,
    unsigned short* __restrict__ hB, unsigned int* __restrict__ outk) {
    int n = blockIdx.x * 256 + threadIdx.x;
    if (n < N_GRAPHS * D) outk[n] = 0x007FFFFFu;   // key(-inf)
    if (n < N_NODES) counts[n] = 0;
    if (blockIdx.x == SCAN_NBLK) {   // block 157: zero the 3 dummy rows
        int t = threadIdx.x;
        if (t < 48) {
            int row = t >> 4, c = t & 15;
            unsigned short* p = (row == 0) ? xb : (row == 1) ? hA : hB;
            u32x4 z = {0u, 0u, 0u, 0u};
            ((u32x4*)(p + (size_t)N_NODES * D))[c] = z;
        }
    }
}

// ---- packed: hist (2500 blk) + x2b (2500 blk) + wprep3 (384 blk) -----------
__global__ void __launch_bounds__(256) k_pack1(
    const int* __restrict__ ei, int* __restrict__ counts,
    const float* __restrict__ x, unsigned int* __restrict__ xb,
    const float* __restrict__ Wr0, const float* __restrict__ Wt0,
    const float* __restrict__ Wr1, const float* __restrict__ Wt1,
    const float* __restrict__ Wr2, const float* __restrict__ Wt2,
    unsigned short* __restrict__ WT) {
    int b = blockIdx.x;
    int t = threadIdx.x;
    if (b < 2500) {
        int e = b * 256 + t;
        atomicAdd(&counts[ei[N_EDGES + e]], 1);
    } else if (b < 5000) {
        int i = (b - 2500) * 256 + t;
        const f32x4* xv = (const f32x4*)x;
        f32x4 v0 = xv[i * 2], v1 = xv[i * 2 + 1];
        u32x4 o;
        o.x = ((unsigned int)f2b(v0.y) << 16) | f2b(v0.x);
        o.y = ((unsigned int)f2b(v0.w) << 16) | f2b(v0.z);
        o.z = ((unsigned int)f2b(v1.y) << 16) | f2b(v1.x);
        o.w = ((unsigned int)f2b(v1.w) << 16) | f2b(v1.z);
        ((u32x4*)xb)[i] = o;
    } else {
        int bw = b - 5000;                 // 0..383
        int l = bw >> 7, c = bw & 127, k = t;
        const float* Wrel = (l == 0) ? Wr0 : (l == 1) ? Wr1 : Wr2;
        const float* Wroot = (l == 0) ? Wt0 : (l == 1) ? Wt1 : Wt2;
        float v = (k < D) ? Wrel[k * D + c] : Wroot[(k - D) * D + c];
        WT[(size_t)l * 128 * 256 + c * 256 + k] = f2b(v);
    }
}

// ---- scan of padded (x16) degrees ------------------------------------------
__global__ void __launch_bounds__(256) k_scan1(const int* __restrict__ counts,
                                               int* __restrict__ local_pre,
                                               int* __restrict__ blocksums) {
    int t = threadIdx.x;
    int i = blockIdx.x * 256 + t;
    int lane = t & 63, wave = t >> 6;
    int v = (i < N_NODES) ? ((counts[i] + 15) & ~15) : 0;   // pad degree to x16
    int incl = v;
#pragma unroll
    for (int off = 1; off < 64; off <<= 1) {
        int u = __shfl_up(incl, off);
        if (lane >= off) incl += u;
    }
    __shared__ int ws[4];
    if (lane == 63) ws[wave] = incl;
    __syncthreads();
    int base = 0;
    for (int w = 0; w < 4; ++w) {
        int s = ws[w];
        if (w < wave) base += s;
    }
    if (i < N_NODES) local_pre[i] = base + incl - v;
    if (t == 255) blocksums[blockIdx.x] = base + incl;
}

// Fused scan2+scan3: block reduces blocksums[0..bid), emits 16-aligned row
// starts + real ends (rend) + cursor. NO dummy fill — k_layer clamps.
__global__ void __launch_bounds__(256) k_scan3(const int* __restrict__ local_pre,
                                               const int* __restrict__ blocksums,
                                               const int* __restrict__ counts,
                                               int* __restrict__ rstart,
                                               int* __restrict__ rend,
                                               int* __restrict__ cursor) {
    int t = threadIdx.x;
    int lane = t & 63, wave = t >> 6;
    int bid = blockIdx.x;
    int v = (t < bid) ? blocksums[t] : 0;   // bid <= 156 < 256
#pragma unroll
    for (int off = 32; off >= 1; off >>= 1) v += __shfl_xor(v, off);
    __shared__ int ws[4];
    if (lane == 0) ws[wave] = v;
    __syncthreads();
    int base = ws[0] + ws[1] + ws[2] + ws[3];   // exclusive prefix for this block

    int i = bid * 256 + t;
    if (i < N_NODES) {
        int rp = base + local_pre[i];
        rstart[i] = rp;
        cursor[i] = rp;
        rend[i] = rp + counts[i];
    }
}

__global__ void k_scatter(const int* __restrict__ ei, int* __restrict__ cursor,
                          int* __restrict__ src_pad) {
    int e = blockIdx.x * blockDim.x + threadIdx.x;
    if (e < N_EDGES) {
        int d = ei[N_EDGES + e];
        int pos = atomicAdd(&cursor[d], 1);
        src_pad[pos] = ei[e];
    }
}

// ---- fused layer: CSR gather-sum (LDS) + MFMA GEMM (+ fused max-pool) ------
// Block = 16 nodes, 4 waves. Lane = (q = node slot lane>>4, c = chunk lane&15).
// Phase 1: 4 nodes per wave in parallel; 16 group-uniform full-row reads per
//   trip. Unfilled pad slots are garbage; per-element clamp to the zero row
//   N_NODES replaces the R8 dummy-fill pass (saves 320K scattered stores).
// Phase 2: GEMM out[16][128] = [aggLDS|X] @ [W_rel;W_root] + b.
// Epilogue: outk==null -> relu+store bf16; else fused global_max_pool.
__global__ void __launch_bounds__(256) k_layer(
    const unsigned short* __restrict__ in,  // [N+1][128] bf16 (row N zero)
    const int* __restrict__ rstart,
    const int* __restrict__ rend,
    const int* __restrict__ src_pad,
    const unsigned short* __restrict__ WT,  // [128][256] bf16 (k contiguous)
    const float* __restrict__ bias,
    unsigned short* __restrict__ out,       // [N+1][128] bf16 (unused if outk)
    const int* __restrict__ batch,
    unsigned int* __restrict__ outk) {      // null for layers 0,1
    __shared__ unsigned int aggLDS[16 * LDS_STRIDE];
    int tid = threadIdx.x;
    int w = tid >> 6;
    int lane = tid & 63;
    int q = lane >> 4;      // node slot / MFMA quad
    int c = lane & 15;      // 16B chunk / MFMA row
    int nl = w * 4 + q;
    int nodebase = blockIdx.x * 16;
    const u32x4* inv = (const u32x4*)in;

    // ---- phase 1: gather-sum ----
    int s = rstart[nodebase + nl];          // 16-aligned
    int e = rend[nodebase + nl];            // real end
    int deg = e - s;
    const int4* sidx = (const int4*)(src_pad + s);
    int ntrips = (deg + 15) >> 4;

    float a0 = 0.f, a1 = 0.f, a2 = 0.f, a3 = 0.f;
    float a4 = 0.f, a5 = 0.f, a6 = 0.f, a7 = 0.f;

#define ACC8(v) do { \
        a0 += blo((v).x); a1 += bhi((v).x); \
        a2 += blo((v).y); a3 += bhi((v).y); \
        a4 += blo((v).z); a5 += bhi((v).z); \
        a6 += blo((v).w); a7 += bhi((v).w); } while (0)
#define CL(idx, k) (((k) < rem) ? (idx) : N_NODES)

    for (int t = 0; t < ntrips; ++t) {
        int rem = deg - (t << 4);           // >= 1 for executed trips
        int4 ia = sidx[4 * t + 0];
        int4 ib = sidx[4 * t + 1];
        int4 ic = sidx[4 * t + 2];
        int4 id = sidx[4 * t + 3];
        u32x4 v0 = inv[ia.x * 16 + c];          // element 0 always valid
        u32x4 v1 = inv[CL(ia.y, 1) * 16 + c];
        u32x4 v2 = inv[CL(ia.z, 2) * 16 + c];
        u32x4 v3 = inv[CL(ia.w, 3) * 16 + c];
        u32x4 v4 = inv[CL(ib.x, 4) * 16 + c];
        u32x4 v5 = inv[CL(ib.y, 5) * 16 + c];
        u32x4 v6 = inv[CL(ib.z, 6) * 16 + c];
        u32x4 v7 = inv[CL(ib.w, 7) * 16 + c];
        u32x4 v8 = inv[CL(ic.x, 8) * 16 + c];
        u32x4 v9 = inv[CL(ic.y, 9) * 16 + c];
        u32x4 va = inv[CL(ic.z, 10) * 16 + c];
        u32x4 vb = inv[CL(ic.w, 11) * 16 + c];
        u32x4 vc = inv[CL(id.x, 12) * 16 + c];
        u32x4 vd = inv[CL(id.y, 13) * 16 + c];
        u32x4 ve = inv[CL(id.z, 14) * 16 + c];
        u32x4 vf = inv[CL(id.w, 15) * 16 + c];
        ACC8(v0); ACC8(v1); ACC8(v2); ACC8(v3);
        ACC8(v4); ACC8(v5); ACC8(v6); ACC8(v7);
        ACC8(v8); ACC8(v9); ACC8(va); ACC8(vb);
        ACC8(vc); ACC8(vd); ACC8(ve); ACC8(vf);
    }
#undef CL
#undef ACC8

    u32x4 o;
    o.x = ((unsigned int)f2b(a1) << 16) | f2b(a0);
    o.y = ((unsigned int)f2b(a3) << 16) | f2b(a2);
    o.z = ((unsigned int)f2b(a5) << 16) | f2b(a4);
    o.w = ((unsigned int)f2b(a7) << 16) | f2b(a6);
    *(u32x4*)&aggLDS[nl * LDS_STRIDE + c * 4] = o;   // linear feats: word i = feats 2i,2i+1
    __syncthreads();

    // ---- phase 2: GEMM ----
    int row = c, quad = q;
    int colbase = w * 32;

    f32x4 acc0 = {0.f, 0.f, 0.f, 0.f};
    f32x4 acc1 = {0.f, 0.f, 0.f, 0.f};

    const unsigned int* Al = &aggLDS[row * LDS_STRIDE];
    const short* Xp = (const short*)(in + (nodebase + row) * D);
    const short* W0 = (const short*)(WT + (colbase + row) * 256);
    const short* W1 = (const short*)(WT + (colbase + 16 + row) * 256);

#pragma unroll
    for (int t = 0; t < 4; ++t) {
        bf16x8 af = *(const bf16x8*)(Al + t * 16 + quad * 4);
        int k0 = t * 32 + quad * 8;
        bf16x8 b0 = *(const bf16x8*)(W0 + k0);
        bf16x8 b1 = *(const bf16x8*)(W1 + k0);
        acc0 = __builtin_amdgcn_mfma_f32_16x16x32_bf16(af, b0, acc0, 0, 0, 0);
        acc1 = __builtin_amdgcn_mfma_f32_16x16x32_bf16(af, b1, acc1, 0, 0, 0);
    }
#pragma unroll
    for (int t = 0; t < 4; ++t) {
        int k0 = t * 32 + quad * 8;
        bf16x8 xf = *(const bf16x8*)(Xp + k0);
        bf16x8 b0 = *(const bf16x8*)(W0 + 128 + k0);
        bf16x8 b1 = *(const bf16x8*)(W1 + 128 + k0);
        acc0 = __builtin_amdgcn_mfma_f32_16x16x32_bf16(xf, b0, acc0, 0, 0, 0);
        acc1 = __builtin_amdgcn_mfma_f32_16x16x32_bf16(xf, b1, acc1, 0, 0, 0);
    }

    int c0 = colbase + row, c1 = c0 + 16;
    float bia0 = bias[c0], bia1 = bias[c1];
    float v0[4], v1[4];
#pragma unroll
    for (int r = 0; r < 4; ++r) { v0[r] = acc0[r] + bia0; v1[r] = acc1[r] + bia1; }

    if (outk == nullptr) {
        // layers 0,1: relu + bf16 store
#pragma unroll
        for (int r = 0; r < 4; ++r) {
            int n2 = nodebase + quad * 4 + r;
            out[n2 * D + c0] = f2b(fmaxf(v0[r], 0.f));
            out[n2 * D + c1] = f2b(fmaxf(v1[r], 0.f));
        }
    } else {
        // layer 2: fused global_max_pool (batch sorted)
        int g0 = batch[nodebase];
        int g15 = batch[nodebase + 15];
        if (g0 == g15) {
            float m0 = fmaxf(fmaxf(v0[0], v0[1]), fmaxf(v0[2], v0[3]));
            float m1 = fmaxf(fmaxf(v1[0], v1[1]), fmaxf(v1[2], v1[3]));
            m0 = fmaxf(m0, __shfl_xor(m0, 16)); m0 = fmaxf(m0, __shfl_xor(m0, 32));
            m1 = fmaxf(m1, __shfl_xor(m1, 16)); m1 = fmaxf(m1, __shfl_xor(m1, 32));
            if (quad == 0) {
                atomicMax(&outk[g0 * D + c0], fkey(m0));
                atomicMax(&outk[g0 * D + c1], fkey(m1));
            }
        } else {  // boundary block (~5%): per-value atomics
#pragma unroll
            for (int r = 0; r < 4; ++r) {
                int gg = batch[nodebase + quad * 4 + r];
                atomicMax(&outk[gg * D + c0], fkey(v0[r]));
                atomicMax(&outk[gg * D + c1], fkey(v1[r]));
            }
        }
    }
}

// ---- unmap keys -> floats (in place over d_out) ----------------------------
__global__ void k_unmap(unsigned int* __restrict__ outk) {
    int i = blockIdx.x * 256 + threadIdx.x;   // 64 blocks x 256 = 16384
    unsigned int k = outk[i];
    unsigned int b = (k & 0x80000000u) ? (k ^ 0x80000000u) : ~k;
    ((float*)outk)[i] = __uint_as_float(b);
}

extern "C" void kernel_launch(void* const* d_in, const int* in_sizes, int n_in,
                              void* d_out, int out_size, void* d_ws, size_t ws_size,
                              hipStream_t stream) {
    const float* x = (const float*)d_in[0];
    const int* ei = (const int*)d_in[1];
    const int* batch = (const int*)d_in[2];
    const float* Wrel[3]  = {(const float*)d_in[3], (const float*)d_in[6], (const float*)d_in[9]};
    const float* brel[3]  = {(const float*)d_in[4], (const float*)d_in[7], (const float*)d_in[10]};
    const float* Wroot[3] = {(const float*)d_in[5], (const float*)d_in[8], (const float*)d_in[11]};
    unsigned int* outk = (unsigned int*)d_out;

    char* ws = (char*)d_ws;
    size_t off = 0;
    auto alloc = [&](size_t bytes) -> void* {
        void* p = ws + off;
        off = (off + bytes + 255) & ~(size_t)255;
        return p;
    };
    // activation buffers have one extra zero row (index N_NODES)
    unsigned short* xb  = (unsigned short*)alloc((size_t)(N_NODES + 1) * D * 2);
    unsigned short* hA  = (unsigned short*)alloc((size_t)(N_NODES + 1) * D * 2);
    unsigned short* hB  = (unsigned short*)alloc((size_t)(N_NODES + 1) * D * 2);
    unsigned short* WT  = (unsigned short*)alloc((size_t)3 * 128 * 256 * 2);
    int* rstart     = (int*)alloc((size_t)N_NODES * 4);
    int* rend       = (int*)alloc((size_t)N_NODES * 4);
    int* counts     = (int*)alloc((size_t)N_NODES * 4);
    int* cursor     = (int*)alloc((size_t)N_NODES * 4);
    int* src_pad    = (int*)alloc((size_t)(N_EDGES + 16 * N_NODES) * 4);
    int* local_pre  = (int*)alloc((size_t)N_NODES * 4);
    int* blocksums  = (int*)alloc((size_t)SCAN_NBLK * 4);

    // init (zero counts + dummy rows + out keys)
    k_init<<<SCAN_NBLK + 1, 256, 0, stream>>>(counts, xb, hA, hB, outk);
    // packed: hist + x2b + wprep3
    k_pack1<<<5384, 256, 0, stream>>>(ei, counts, x, (unsigned int*)xb,
                                      Wrel[0], Wroot[0], Wrel[1], Wroot[1],
                                      Wrel[2], Wroot[2], WT);
    // scan (padded degrees) -> 16-aligned starts + real ends; then scatter
    k_scan1<<<SCAN_NBLK, 256, 0, stream>>>(counts, local_pre, blocksums);
    k_scan3<<<SCAN_NBLK, 256, 0, stream>>>(local_pre, blocksums, counts,
                                           rstart, rend, cursor);
    k_scatter<<<(N_EDGES + 255) / 256, 256, 0, stream>>>(ei, cursor, src_pad);

    // 3 fused GraphConv layers; layer 2 folds the global max pool
    k_layer<<<N_NODES / 16, 256, 0, stream>>>(xb, rstart, rend, src_pad, WT,
                                              brel[0], hA, batch, nullptr);
    k_layer<<<N_NODES / 16, 256, 0, stream>>>(hA, rstart, rend, src_pad, WT + 128 * 256,
                                              brel[1], hB, batch, nullptr);
    k_layer<<<N_NODES / 16, 256, 0, stream>>>(hB, rstart, rend, src_pad, WT + 2 * 128 * 256,
                                              brel[2], hB, batch, outk);

    // keys -> floats
    k_unmap<<<N_GRAPHS * D / 256, 256, 0, stream>>>(outk);
}

// Round 11
// 273.011 us; speedup vs baseline: 1.0840x; 1.0324x over previous
//
#include <hip/hip_runtime.h>
#include <hip/hip_bf16.h>
#include <math.h>

#define N_NODES 40000
#define N_EDGES 640000
#define D 128
#define N_GRAPHS 128
#define SCAN_NBLK ((N_NODES + 255) / 256)   // 157
#define LDS_STRIDE 68                        // words per agg row (pad vs 64 to spread banks)

typedef __attribute__((ext_vector_type(8))) short bf16x8;
typedef __attribute__((ext_vector_type(4))) float f32x4;
typedef __attribute__((ext_vector_type(4))) unsigned int u32x4;

static __device__ __forceinline__ unsigned short f2b(float f) {
    unsigned int u = __float_as_uint(f);
    unsigned int r = (u + 0x7fffu + ((u >> 16) & 1u)) >> 16;  // RNE
    return (unsigned short)r;
}
static __device__ __forceinline__ float blo(unsigned int u) {
    return __uint_as_float(u << 16);
}
static __device__ __forceinline__ float bhi(unsigned int u) {
    return __uint_as_float(u & 0xffff0000u);
}
// monotonic f32 -> u32 key (unsigned order == float order)
static __device__ __forceinline__ unsigned int fkey(float x) {
    unsigned int b = __float_as_uint(x);
    return (b & 0x80000000u) ? ~b : (b | 0x80000000u);
}

// ---- init: zero counts + dummy rows, seed out keys -------------------------
__global__ void __launch_bounds__(256) k_init(
    int* __restrict__ counts,
    unsigned short* __restrict__ xb, unsigned short* __restrict__ hA,
    unsigned short* __restrict__ hB, unsigned int* __restrict__ outk) {
    int n = blockIdx.x * 256 + threadIdx.x;
    if (n < N_GRAPHS * D) outk[n] = 0x007FFFFFu;   // key(-inf)
    if (n < N_NODES) counts[n] = 0;
    if (blockIdx.x == SCAN_NBLK) {   // block 157: zero the 3 dummy rows
        int t = threadIdx.x;
        if (t < 48) {
            int row = t >> 4, c = t & 15;
            unsigned short* p = (row == 0) ? xb : (row == 1) ? hA : hB;
            u32x4 z = {0u, 0u, 0u, 0u};
            ((u32x4*)(p + (size_t)N_NODES * D))[c] = z;
        }
    }
}

// ---- packed: hist (2500 blk) + x2b (2500 blk) + wprep3 (384 blk) -----------
__global__ void __launch_bounds__(256) k_pack1(
    const int* __restrict__ ei, int* __restrict__ counts,
    const float* __restrict__ x, unsigned int* __restrict__ xb,
    const float* __restrict__ Wr0, const float* __restrict__ Wt0,
    const float* __restrict__ Wr1, const float* __restrict__ Wt1,
    const float* __restrict__ Wr2, const float* __restrict__ Wt2,
    unsigned short* __restrict__ WT) {
    int b = blockIdx.x;
    int t = threadIdx.x;
    if (b < 2500) {
        int e = b * 256 + t;
        atomicAdd(&counts[ei[N_EDGES + e]], 1);
    } else if (b < 5000) {
        int i = (b - 2500) * 256 + t;
        const f32x4* xv = (const f32x4*)x;
        f32x4 v0 = xv[i * 2], v1 = xv[i * 2 + 1];
        u32x4 o;
        o.x = ((unsigned int)f2b(v0.y) << 16) | f2b(v0.x);
        o.y = ((unsigned int)f2b(v0.w) << 16) | f2b(v0.z);
        o.z = ((unsigned int)f2b(v1.y) << 16) | f2b(v1.x);
        o.w = ((unsigned int)f2b(v1.w) << 16) | f2b(v1.z);
        ((u32x4*)xb)[i] = o;
    } else {
        int bw = b - 5000;                 // 0..383
        int l = bw >> 7, c = bw & 127, k = t;
        const float* Wrel = (l == 0) ? Wr0 : (l == 1) ? Wr1 : Wr2;
        const float* Wroot = (l == 0) ? Wt0 : (l == 1) ? Wt1 : Wt2;
        float v = (k < D) ? Wrel[k * D + c] : Wroot[(k - D) * D + c];
        WT[(size_t)l * 128 * 256 + c * 256 + k] = f2b(v);
    }
}

// ---- scan of padded (x16) degrees ------------------------------------------
__global__ void __launch_bounds__(256) k_scan1(const int* __restrict__ counts,
                                               int* __restrict__ local_pre,
                                               int* __restrict__ blocksums) {
    int t = threadIdx.x;
    int i = blockIdx.x * 256 + t;
    int lane = t & 63, wave = t >> 6;
    int v = (i < N_NODES) ? ((counts[i] + 15) & ~15) : 0;   // pad degree to x16
    int incl = v;
#pragma unroll
    for (int off = 1; off < 64; off <<= 1) {
        int u = __shfl_up(incl, off);
        if (lane >= off) incl += u;
    }
    __shared__ int ws[4];
    if (lane == 63) ws[wave] = incl;
    __syncthreads();
    int base = 0;
    for (int w = 0; w < 4; ++w) {
        int s = ws[w];
        if (w < wave) base += s;
    }
    if (i < N_NODES) local_pre[i] = base + incl - v;
    if (t == 255) blocksums[blockIdx.x] = base + incl;
}

// Fused scan2+scan3: block reduces blocksums[0..bid), emits row starts +
// cursor + dummy-slot fill (zero-row index N_NODES).
__global__ void __launch_bounds__(256) k_scan3(const int* __restrict__ local_pre,
                                               const int* __restrict__ blocksums,
                                               const int* __restrict__ counts,
                                               int* __restrict__ rp_pad,
                                               int* __restrict__ cursor,
                                               int* __restrict__ src_pad) {
    int t = threadIdx.x;
    int lane = t & 63, wave = t >> 6;
    int bid = blockIdx.x;
    int v = (t < bid) ? blocksums[t] : 0;   // bid <= 156 < 256
#pragma unroll
    for (int off = 32; off >= 1; off >>= 1) v += __shfl_xor(v, off);
    __shared__ int ws[4];
    if (lane == 0) ws[wave] = v;
    __syncthreads();
    int base = ws[0] + ws[1] + ws[2] + ws[3];   // exclusive prefix for this block

    int i = bid * 256 + t;
    if (i < N_NODES) {
        int rp = base + local_pre[i];
        rp_pad[i] = rp;
        cursor[i] = rp;
        int c = counts[i];
        int pc = (c + 15) & ~15;
        for (int j = rp + c; j < rp + pc; ++j) src_pad[j] = N_NODES;
        if (i == N_NODES - 1) rp_pad[N_NODES] = rp + pc;
    }
}

__global__ void k_scatter(const int* __restrict__ ei, int* __restrict__ cursor,
                          int* __restrict__ src_pad) {
    int e = blockIdx.x * blockDim.x + threadIdx.x;
    if (e < N_EDGES) {
        int d = ei[N_EDGES + e];
        int pos = atomicAdd(&cursor[d], 1);
        src_pad[pos] = ei[e];
    }
}

// ---- fused layer: CSR gather-sum (LDS) + MFMA GEMM (+ fused max-pool) ------
// Block = 16 nodes, 4 waves. Lane = (q = node slot lane>>4, c = chunk lane&15).
// Phase 1: 4 nodes per wave in parallel; 16 group-uniform full-row reads per
//   trip (contiguous 256B segments). Segments padded to x16 with zero row.
// Phase 2: GEMM out[16][128] = [aggLDS|X] @ [W_rel;W_root] + b. All phase-2
//   loads issued AFTER the barrier: keeping VGPR<=64 (8 waves/SIMD) beats
//   hoisting (R7: 76 VGPR -> occ 25%, +4us/layer) and branch-free clamping
//   (R10: +1us/layer VALU). This config is the measured optimum of R4-R10.
// Epilogue: outk==null -> relu+store bf16; else fold global_max_pool.
__global__ void __launch_bounds__(256) k_layer(
    const unsigned short* __restrict__ in,  // [N+1][128] bf16 (row N zero)
    const int* __restrict__ rp_pad,
    const int* __restrict__ src_pad,
    const unsigned short* __restrict__ WT,  // [128][256] bf16 (k contiguous)
    const float* __restrict__ bias,
    unsigned short* __restrict__ out,       // [N+1][128] bf16 (unused if outk)
    const int* __restrict__ batch,
    unsigned int* __restrict__ outk) {      // null for layers 0,1
    __shared__ unsigned int aggLDS[16 * LDS_STRIDE];
    int tid = threadIdx.x;
    int w = tid >> 6;
    int lane = tid & 63;
    int q = lane >> 4;      // node slot / MFMA quad
    int c = lane & 15;      // 16B chunk / MFMA row
    int nl = w * 4 + q;
    int nodebase = blockIdx.x * 16;
    const u32x4* inv = (const u32x4*)in;

    // ---- phase 1: gather-sum ----
    int s = rp_pad[nodebase + nl];
    int e = rp_pad[nodebase + nl + 1];
    const int4* sidx = (const int4*)(src_pad + s);
    int ntrips = (e - s) >> 4;

    float a0 = 0.f, a1 = 0.f, a2 = 0.f, a3 = 0.f;
    float a4 = 0.f, a5 = 0.f, a6 = 0.f, a7 = 0.f;

#define ACC8(v) do { \
        a0 += blo((v).x); a1 += bhi((v).x); \
        a2 += blo((v).y); a3 += bhi((v).y); \
        a4 += blo((v).z); a5 += bhi((v).z); \
        a6 += blo((v).w); a7 += bhi((v).w); } while (0)

    for (int t = 0; t < ntrips; ++t) {
        int4 ia = sidx[4 * t + 0];
        int4 ib = sidx[4 * t + 1];
        int4 ic = sidx[4 * t + 2];
        int4 id = sidx[4 * t + 3];
        u32x4 v0 = inv[ia.x * 16 + c];
        u32x4 v1 = inv[ia.y * 16 + c];
        u32x4 v2 = inv[ia.z * 16 + c];
        u32x4 v3 = inv[ia.w * 16 + c];
        u32x4 v4 = inv[ib.x * 16 + c];
        u32x4 v5 = inv[ib.y * 16 + c];
        u32x4 v6 = inv[ib.z * 16 + c];
        u32x4 v7 = inv[ib.w * 16 + c];
        u32x4 v8 = inv[ic.x * 16 + c];
        u32x4 v9 = inv[ic.y * 16 + c];
        u32x4 va = inv[ic.z * 16 + c];
        u32x4 vb = inv[ic.w * 16 + c];
        u32x4 vc = inv[id.x * 16 + c];
        u32x4 vd = inv[id.y * 16 + c];
        u32x4 ve = inv[id.z * 16 + c];
        u32x4 vf = inv[id.w * 16 + c];
        ACC8(v0); ACC8(v1); ACC8(v2); ACC8(v3);
        ACC8(v4); ACC8(v5); ACC8(v6); ACC8(v7);
        ACC8(v8); ACC8(v9); ACC8(va); ACC8(vb);
        ACC8(vc); ACC8(vd); ACC8(ve); ACC8(vf);
    }
#undef ACC8

    u32x4 o;
    o.x = ((unsigned int)f2b(a1) << 16) | f2b(a0);
    o.y = ((unsigned int)f2b(a3) << 16) | f2b(a2);
    o.z = ((unsigned int)f2b(a5) << 16) | f2b(a4);
    o.w = ((unsigned int)f2b(a7) << 16) | f2b(a6);
    *(u32x4*)&aggLDS[nl * LDS_STRIDE + c * 4] = o;   // linear feats: word i = feats 2i,2i+1
    __syncthreads();

    // ---- phase 2: GEMM ----
    int row = c, quad = q;
    int colbase = w * 32;

    f32x4 acc0 = {0.f, 0.f, 0.f, 0.f};
    f32x4 acc1 = {0.f, 0.f, 0.f, 0.f};

    const unsigned int* Al = &aggLDS[row * LDS_STRIDE];
    const short* Xp = (const short*)(in + (nodebase + row) * D);
    const short* W0 = (const short*)(WT + (colbase + row) * 256);
    const short* W1 = (const short*)(WT + (colbase + 16 + row) * 256);

#pragma unroll
    for (int t = 0; t < 4; ++t) {
        bf16x8 af = *(const bf16x8*)(Al + t * 16 + quad * 4);
        int k0 = t * 32 + quad * 8;
        bf16x8 b0 = *(const bf16x8*)(W0 + k0);
        bf16x8 b1 = *(const bf16x8*)(W1 + k0);
        acc0 = __builtin_amdgcn_mfma_f32_16x16x32_bf16(af, b0, acc0, 0, 0, 0);
        acc1 = __builtin_amdgcn_mfma_f32_16x16x32_bf16(af, b1, acc1, 0, 0, 0);
    }
#pragma unroll
    for (int t = 0; t < 4; ++t) {
        int k0 = t * 32 + quad * 8;
        bf16x8 xf = *(const bf16x8*)(Xp + k0);
        bf16x8 b0 = *(const bf16x8*)(W0 + 128 + k0);
        bf16x8 b1 = *(const bf16x8*)(W1 + 128 + k0);
        acc0 = __builtin_amdgcn_mfma_f32_16x16x32_bf16(xf, b0, acc0, 0, 0, 0);
        acc1 = __builtin_amdgcn_mfma_f32_16x16x32_bf16(xf, b1, acc1, 0, 0, 0);
    }

    int c0 = colbase + row, c1 = c0 + 16;
    float bia0 = bias[c0], bia1 = bias[c1];
    float v0[4], v1[4];
#pragma unroll
    for (int r = 0; r < 4; ++r) { v0[r] = acc0[r] + bia0; v1[r] = acc1[r] + bia1; }

    if (outk == nullptr) {
        // layers 0,1: relu + bf16 store
#pragma unroll
        for (int r = 0; r < 4; ++r) {
            int n2 = nodebase + quad * 4 + r;
            out[n2 * D + c0] = f2b(fmaxf(v0[r], 0.f));
            out[n2 * D + c1] = f2b(fmaxf(v1[r], 0.f));
        }
    } else {
        // layer 2: fused global_max_pool (batch sorted)
        int g0 = batch[nodebase];
        int g15 = batch[nodebase + 15];
        if (g0 == g15) {
            float m0 = fmaxf(fmaxf(v0[0], v0[1]), fmaxf(v0[2], v0[3]));
            float m1 = fmaxf(fmaxf(v1[0], v1[1]), fmaxf(v1[2], v1[3]));
            m0 = fmaxf(m0, __shfl_xor(m0, 16)); m0 = fmaxf(m0, __shfl_xor(m0, 32));
            m1 = fmaxf(m1, __shfl_xor(m1, 16)); m1 = fmaxf(m1, __shfl_xor(m1, 32));
            if (quad == 0) {
                atomicMax(&outk[g0 * D + c0], fkey(m0));
                atomicMax(&outk[g0 * D + c1], fkey(m1));
            }
        } else {  // boundary block (~5%): per-value atomics
#pragma unroll
            for (int r = 0; r < 4; ++r) {
                int gg = batch[nodebase + quad * 4 + r];
                atomicMax(&outk[gg * D + c0], fkey(v0[r]));
                atomicMax(&outk[gg * D + c1], fkey(v1[r]));
            }
        }
    }
}

// ---- unmap keys -> floats (in place over d_out) ----------------------------
__global__ void k_unmap(unsigned int* __restrict__ outk) {
    int i = blockIdx.x * 256 + threadIdx.x;   // 64 blocks x 256 = 16384
    unsigned int k = outk[i];
    unsigned int b = (k & 0x80000000u) ? (k ^ 0x80000000u) : ~k;
    ((float*)outk)[i] = __uint_as_float(b);
}

extern "C" void kernel_launch(void* const* d_in, const int* in_sizes, int n_in,
                              void* d_out, int out_size, void* d_ws, size_t ws_size,
                              hipStream_t stream) {
    const float* x = (const float*)d_in[0];
    const int* ei = (const int*)d_in[1];
    const int* batch = (const int*)d_in[2];
    const float* Wrel[3]  = {(const float*)d_in[3], (const float*)d_in[6], (const float*)d_in[9]};
    const float* brel[3]  = {(const float*)d_in[4], (const float*)d_in[7], (const float*)d_in[10]};
    const float* Wroot[3] = {(const float*)d_in[5], (const float*)d_in[8], (const float*)d_in[11]};
    unsigned int* outk = (unsigned int*)d_out;

    char* ws = (char*)d_ws;
    size_t off = 0;
    auto alloc = [&](size_t bytes) -> void* {
        void* p = ws + off;
        off = (off + bytes + 255) & ~(size_t)255;
        return p;
    };
    // activation buffers have one extra zero row (index N_NODES)
    unsigned short* xb  = (unsigned short*)alloc((size_t)(N_NODES + 1) * D * 2);
    unsigned short* hA  = (unsigned short*)alloc((size_t)(N_NODES + 1) * D * 2);
    unsigned short* hB  = (unsigned short*)alloc((size_t)(N_NODES + 1) * D * 2);
    unsigned short* WT  = (unsigned short*)alloc((size_t)3 * 128 * 256 * 2);
    int* rp_pad     = (int*)alloc((size_t)(N_NODES + 1) * 4);
    int* counts     = (int*)alloc((size_t)N_NODES * 4);
    int* cursor     = (int*)alloc((size_t)N_NODES * 4);
    int* src_pad    = (int*)alloc((size_t)(N_EDGES + 16 * N_NODES) * 4);
    int* local_pre  = (int*)alloc((size_t)N_NODES * 4);
    int* blocksums  = (int*)alloc((size_t)SCAN_NBLK * 4);

    // init (zero counts + dummy rows + out keys)
    k_init<<<SCAN_NBLK + 1, 256, 0, stream>>>(counts, xb, hA, hB, outk);
    // packed: hist + x2b + wprep3
    k_pack1<<<5384, 256, 0, stream>>>(ei, counts, x, (unsigned int*)xb,
                                      Wrel[0], Wroot[0], Wrel[1], Wroot[1],
                                      Wrel[2], Wroot[2], WT);
    // scan (padded degrees) + dummy fill + scatter
    k_scan1<<<SCAN_NBLK, 256, 0, stream>>>(counts, local_pre, blocksums);
    k_scan3<<<SCAN_NBLK, 256, 0, stream>>>(local_pre, blocksums, counts,
                                           rp_pad, cursor, src_pad);
    k_scatter<<<(N_EDGES + 255) / 256, 256, 0, stream>>>(ei, cursor, src_pad);

    // 3 fused GraphConv layers; layer 2 folds the global max pool
    k_layer<<<N_NODES / 16, 256, 0, stream>>>(xb, rp_pad, src_pad, WT,
                                              brel[0], hA, batch, nullptr);
    k_layer<<<N_NODES / 16, 256, 0, stream>>>(hA, rp_pad, src_pad, WT + 128 * 256,
                                              brel[1], hB, batch, nullptr);
    k_layer<<<N_NODES / 16, 256, 0, stream>>>(hB, rp_pad, src_pad, WT + 2 * 128 * 256,
                                              brel[2], hB, batch, outk);

    // keys -> floats
    k_unmap<<<N_GRAPHS * D / 256, 256, 0, stream>>>(outk);
}